// Round 8
// baseline (43.838 us; speedup 1.0000x reference)
//
#include <hip/hip_runtime.h>
#include <float.h>

typedef __attribute__((ext_vector_type(8))) short short8;
typedef __attribute__((ext_vector_type(4))) float f32x4;

#define SLOPE 0.2f
// leaky(t) = 0.6t + 0.4|t| for slope 0.2

__device__ __forceinline__ float leaky(float x) { return fmaxf(x, SLOPE * x); }

// f32 -> bf16 round-to-nearest-even
__device__ __forceinline__ unsigned short f2bf(float f) {
  unsigned u = __float_as_uint(f);
  return (unsigned short)((u + 0x7FFFu + ((u >> 16) & 1u)) >> 16);
}

// ---------------------------------------------------------------------------
// Kernel 1 "prep":
//  blocks 0..63   = edge transpose + bit-pack: ep[b][i][jt] u64, bit l =
//                   (edges[b][jt*64+l][i] != 0). Scheduled FIRST (no tail).
//  blocks 64..575 = node MLPs, 8 nodes/block, 2/wave, with ALL weights
//                   staged through a shared 32KB LDS buffer per stage so the
//                   4 waves share one global read (was: per-wave streams,
//                   268MB chip-wide, latency-bound).
// ---------------------------------------------------------------------------
__global__ __launch_bounds__(256) void prep(
    const float* __restrict__ nodes, const int* __restrict__ edges,
    const float* __restrict__ self_w1, const float* __restrict__ self_b1,
    const float* __restrict__ self_w2, const float* __restrict__ self_b2,
    const float* __restrict__ nb_w1,   const float* __restrict__ nb_b1,
    const float* __restrict__ nb_w2,   const float* __restrict__ nb_b2,
    const float* __restrict__ comb_w1, const float* __restrict__ comb_b1,
    const float* __restrict__ comb_w2, const float* __restrict__ comb_b2,
    float* __restrict__ self_e, float* __restrict__ ss, float* __restrict__ sn,
    float* __restrict__ sP, float* __restrict__ sQ,
    unsigned short* __restrict__ nbT, unsigned long long* __restrict__ ep)
{
  __shared__ __align__(16) float wbuf[8192];   // 32 KB: stage weights / edge tile
  __shared__ float x_sh[8][128];
  __shared__ float h_sh[8][64];
  __shared__ float e_sh[8][64];

  const int tid = threadIdx.x, lane = tid & 63, wv = tid >> 6;

  if (blockIdx.x < 64) {
    // ---------------- epack: one 64-i x 512-j strip per block --------------
    int* t_sh = (int*)wbuf;                  // [64][65] = 16.6 KB
    const int blk = blockIdx.x;
    const int b = blk >> 3, it = blk & 7;
    const int i0 = it * 64;
    for (int jt = 0; jt < 8; ++jt) {
      #pragma unroll
      for (int r = 0; r < 4; ++r) {
        const int idx = r * 256 + tid;       // 0..1023 int4s
        const int jr = idx >> 4, i4 = (idx & 15) * 4;
        *(int4*)&t_sh[jr * 65 + i4] =
            *(const int4*)&edges[((size_t)(b * 512 + jt * 64 + jr)) * 512 + i0 + i4];
      }
      __syncthreads();
      #pragma unroll
      for (int u = 0; u < 16; ++u) {
        const int ic = wv * 16 + u;
        const unsigned long long m = __ballot(t_sh[lane * 65 + ic] != 0);
        if (lane == 0) ep[((size_t)(b * 512 + i0 + ic)) * 8 + jt] = m;
      }
      __syncthreads();
    }
    return;
  }

  // ---------------- node MLPs: 8 nodes/block, weights via LDS --------------
  const int node0 = (blockIdx.x - 64) * 8;
  const int bb = node0 >> 9;          // batch
  const int jloc = node0 & 511;       // batch-local node base

  ((float4*)&x_sh[0][0])[tid] = ((const float4*)(nodes + (size_t)node0 * 128))[tid];
  // (barrier below after first weight stage covers x_sh too)

  const int la = wv * 2, lb = la + 1;
  const float w2lane = comb_w2[lane];
  const float cb2 = comb_b2[0];
  const float cb1 = comb_b1[lane];

  for (int p = 0; p < 2; ++p) {
    const float* w1 = p ? nb_w1 : self_w1;
    const float* b1 = p ? nb_b1 : self_b1;
    const float* w2 = p ? nb_w2 : self_w2;
    const float* b2 = p ? nb_b2 : self_b2;
    const float* cw = comb_w1 + (p ? 64 * 64 : 0);

    // ---- stage w1 (128x64 f32 = 32 KB) ----
    {
      const float4* src = (const float4*)w1;
      float4* dst = (float4*)wbuf;
      #pragma unroll
      for (int i = 0; i < 8; ++i) dst[i * 256 + tid] = src[i * 256 + tid];
    }
    __syncthreads();

    // ---- layer 1: h = leaky(x @ w1 + b1) ----
    float a0 = 0.f, a1 = 0.f, c0 = 0.f, c1 = 0.f;
    #pragma unroll 8
    for (int q = 0; q < 32; ++q) {
      float4 xa = *(const float4*)&x_sh[la][q * 4];
      float4 xb = *(const float4*)&x_sh[lb][q * 4];
      float w_0 = wbuf[(q * 4 + 0) * 64 + lane];
      float w_1 = wbuf[(q * 4 + 1) * 64 + lane];
      float w_2 = wbuf[(q * 4 + 2) * 64 + lane];
      float w_3 = wbuf[(q * 4 + 3) * 64 + lane];
      a0 += xa.x * w_0; a1 += xa.y * w_1; a0 += xa.z * w_2; a1 += xa.w * w_3;
      c0 += xb.x * w_0; c1 += xb.y * w_1; c0 += xb.z * w_2; c1 += xb.w * w_3;
    }
    {
      float bv = b1[lane];
      h_sh[la][lane] = leaky(a0 + a1 + bv);
      h_sh[lb][lane] = leaky(c0 + c1 + bv);
    }
    __syncthreads();                 // h_sh visible; wbuf free

    // ---- stage w2 (64x64 f32 = 16 KB) ----
    {
      const float4* src = (const float4*)w2;
      float4* dst = (float4*)wbuf;
      #pragma unroll
      for (int i = 0; i < 4; ++i) dst[i * 256 + tid] = src[i * 256 + tid];
    }
    __syncthreads();

    // ---- layer 2: e = h @ w2 + b2 ----
    a0 = a1 = c0 = c1 = 0.f;
    #pragma unroll 8
    for (int q = 0; q < 16; ++q) {
      float4 ha = *(const float4*)&h_sh[la][q * 4];
      float4 hb = *(const float4*)&h_sh[lb][q * 4];
      float w_0 = wbuf[(q * 4 + 0) * 64 + lane];
      float w_1 = wbuf[(q * 4 + 1) * 64 + lane];
      float w_2 = wbuf[(q * 4 + 2) * 64 + lane];
      float w_3 = wbuf[(q * 4 + 3) * 64 + lane];
      a0 += ha.x * w_0; a1 += ha.y * w_1; a0 += ha.z * w_2; a1 += ha.w * w_3;
      c0 += hb.x * w_0; c1 += hb.y * w_1; c0 += hb.z * w_2; c1 += hb.w * w_3;
    }
    float e_a, e_b;
    {
      float bv = b2[lane];
      e_a = a0 + a1 + bv;
      e_b = c0 + c1 + bv;
    }
    e_sh[la][lane] = e_a;
    e_sh[lb][lane] = e_b;
    if (p == 0) {
      self_e[(size_t)(node0 + la) * 64 + lane] = e_a;
      self_e[(size_t)(node0 + lb) * 64 + lane] = e_b;
    }
    __syncthreads();                 // e_sh visible; wbuf free

    // ---- stage cw (64x64 f32 = 16 KB) ----
    {
      const float4* src = (const float4*)cw;
      float4* dst = (float4*)wbuf;
      #pragma unroll
      for (int i = 0; i < 4; ++i) dst[i * 256 + tid] = src[i * 256 + tid];
    }
    __syncthreads();

    // ---- projection: s = e @ cw (+ comb_b1 for self path) ----
    a0 = a1 = c0 = c1 = 0.f;
    #pragma unroll 8
    for (int q = 0; q < 16; ++q) {
      float4 ea = *(const float4*)&e_sh[la][q * 4];
      float4 eb = *(const float4*)&e_sh[lb][q * 4];
      float w_0 = wbuf[(q * 4 + 0) * 64 + lane];
      float w_1 = wbuf[(q * 4 + 1) * 64 + lane];
      float w_2 = wbuf[(q * 4 + 2) * 64 + lane];
      float w_3 = wbuf[(q * 4 + 3) * 64 + lane];
      a0 += ea.x * w_0; a1 += ea.y * w_1; a0 += ea.z * w_2; a1 += ea.w * w_3;
      c0 += eb.x * w_0; c1 += eb.y * w_1; c0 += eb.z * w_2; c1 += eb.w * w_3;
    }
    float s_a = a0 + a1 + (p ? 0.f : cb1);
    float s_b = c0 + c1 + (p ? 0.f : cb1);
    {
      float* so = p ? sn : ss;
      so[(size_t)(node0 + la) * 64 + lane] = s_a;
      so[(size_t)(node0 + lb) * 64 + lane] = s_b;
    }
    float ra = w2lane * s_a, rb = w2lane * s_b;
    #pragma unroll
    for (int off = 32; off; off >>= 1) {
      ra += __shfl_xor(ra, off);
      rb += __shfl_xor(rb, off);
    }
    if (lane == 0) {
      float* po = p ? sQ : sP;
      float add = p ? 0.f : cb2;
      po[node0 + la] = 0.6f * ra + add;
      po[node0 + lb] = 0.6f * rb + add;
    }

    if (p == 1) {
      // nbT[b][h=lane][j]
      unsigned pack = (unsigned)f2bf(e_a) | ((unsigned)f2bf(e_b) << 16);
      *(unsigned*)(nbT + ((size_t)(bb * 64 + lane) * 512 + jloc + la)) = pack;
    }
    __syncthreads();                 // wbuf free for next path
  }
}

// ---------------------------------------------------------------------------
// Kernel B: 256 blocks (b = blk&7), 16 rows/block, 512 thr (8 waves).
// Wave wv owns rows {2wv, 2wv+1}: scores in registers, in-wave softmax,
// bf16 P -> LDS, MFMA aggregation (B straight from global, L2-hot).
// Edge masks come from pre-packed ep (wave-uniform u64 loads).
// ---------------------------------------------------------------------------
__global__ __launch_bounds__(512) void gat_attn(
    const unsigned long long* __restrict__ ep,
    const float* __restrict__ comb_w2,
    const float* __restrict__ self_e,
    const float* __restrict__ ss, const float* __restrict__ sn,
    const float* __restrict__ sP, const float* __restrict__ sQ,
    const unsigned short* __restrict__ nbT,
    float* __restrict__ out)
{
  __shared__ __align__(16) float sn_sh[2][64][68];          // 34.8 KB dbuf
  __shared__ __align__(16) unsigned short P_sh[16][520];    // 16.6 KB
  __shared__ __align__(16) float red_sh[4][64][4];          // 4 KB
  __shared__ float f_sh[16];

  const int tid = threadIdx.x, lane = tid & 63, wv = tid >> 6;
  const int b = blockIdx.x & 7, it = blockIdx.x >> 3;
  const int i0 = it * 16;
  const size_t nodeb = (size_t)b * 512;

  const int ra = wv * 2, rb = ra + 1;     // local rows (wave-owned)
  const int ia = i0 + ra, ib = ia + 1;    // batch-local rows

  // ---- edge masks from bit-packed ep (wave-uniform loads) + sQ ----
  unsigned em0 = 0, em1 = 0;
  float sQv[8];
  {
    const unsigned long long* e0 = ep + (nodeb + ia) * 8;
    const unsigned long long* e1 = ep + (nodeb + ib) * 8;
    #pragma unroll
    for (int jt = 0; jt < 8; ++jt) {
      em0 |= (unsigned)((e0[jt] >> lane) & 1ull) << jt;
      em1 |= (unsigned)((e1[jt] >> lane) & 1ull) << jt;
      sQv[jt] = sQ[nodeb + jt * 64 + lane];
    }
  }
  {
    const int d0 = ia - lane;             // self-loop: jt*64+lane == ia
    if (d0 >= 0 && (d0 & 63) == 0) em0 &= ~(1u << (d0 >> 6));
    const int d1 = ib - lane;
    if (d1 >= 0 && (d1 & 63) == 0) em1 &= ~(1u << (d1 >> 6));
  }

  // ---- hoist: w2p (0.4*w2), ss rows, sP scalars -> registers ----
  float4 w2p[16], sa0[16], sa1[16];
  {
    const float4* w2v = (const float4*)comb_w2;
    const float4* s0 = (const float4*)(ss + (nodeb + ia) * 64);
    const float4* s1 = (const float4*)(ss + (nodeb + ib) * 64);
    #pragma unroll
    for (int q = 0; q < 16; ++q) {
      float4 w = w2v[q];
      w2p[q] = make_float4(0.4f * w.x, 0.4f * w.y, 0.4f * w.z, 0.4f * w.w);
      sa0[q] = s0[q];
      sa1[q] = s1[q];
    }
  }
  const float sPa = sP[nodeb + ia], sPb = sP[nodeb + ib];

  // ---- phase 1: scores, double-buffered sn staging (1 barrier/tile) ----
  const int str = tid >> 4, stc = (tid & 15) * 4;
  const int str2 = (tid + 512) >> 4, stc2 = ((tid + 512) & 15) * 4;
  float4 st0, st1;
  {
    const float4* src = (const float4*)(sn + nodeb * 64);
    st0 = src[tid];
    st1 = src[tid + 512];
  }

  float msc0[8], msc1[8];
  int cur = 0;
  for (int jt = 0; jt < 8; ++jt) {
    *(float4*)&sn_sh[cur][str][stc] = st0;
    *(float4*)&sn_sh[cur][str2][stc2] = st1;
    if (jt < 7) {
      const float4* src = (const float4*)(sn + (nodeb + (jt + 1) * 64) * 64);
      st0 = src[tid];
      st1 = src[tid + 512];
    }
    __syncthreads();

    float acc0 = 0.f, acc1 = 0.f;
    #pragma unroll
    for (int q = 0; q < 16; ++q) {
      float4 v = *(const float4*)&sn_sh[cur][lane][q * 4];
      float4 w = w2p[q];
      float4 A = sa0[q];
      float4 Bv = sa1[q];
      acc0 += w.x * fabsf(A.x + v.x) + w.y * fabsf(A.y + v.y)
            + w.z * fabsf(A.z + v.z) + w.w * fabsf(A.w + v.w);
      acc1 += w.x * fabsf(Bv.x + v.x) + w.y * fabsf(Bv.y + v.y)
            + w.z * fabsf(Bv.z + v.z) + w.w * fabsf(Bv.w + v.w);
    }
    msc0[jt] = ((em0 >> jt) & 1u) ? acc0 + sPa + sQv[jt] : -FLT_MAX;
    msc1[jt] = ((em1 >> jt) & 1u) ? acc1 + sPb + sQv[jt] : -FLT_MAX;
    cur ^= 1;
  }

  // ---- phase 2: in-wave softmax (rows wholly owned by this wave) ----
  float m0 = msc0[0], m1 = msc1[0];
  #pragma unroll
  for (int jt = 1; jt < 8; ++jt) {
    m0 = fmaxf(m0, msc0[jt]);
    m1 = fmaxf(m1, msc1[jt]);
  }
  #pragma unroll
  for (int off = 32; off; off >>= 1) {
    m0 = fmaxf(m0, __shfl_xor(m0, off));
    m1 = fmaxf(m1, __shfl_xor(m1, off));
  }

  float s0 = 0.f, s1 = 0.f;
  #pragma unroll
  for (int jt = 0; jt < 8; ++jt) {
    const float e0 = __expf(msc0[jt] - m0);
    const float e1 = __expf(msc1[jt] - m1);
    P_sh[ra][jt * 64 + lane] = f2bf(e0);
    P_sh[rb][jt * 64 + lane] = f2bf(e1);
    s0 += e0;
    s1 += e1;
  }
  #pragma unroll
  for (int off = 32; off; off >>= 1) {
    s0 += __shfl_xor(s0, off);
    s1 += __shfl_xor(s1, off);
  }
  if (lane == 0) {
    f_sh[ra] = (m0 > -1e37f) ? 1.0f / s0 : 0.0f;
    f_sh[rb] = (m1 > -1e37f) ? 1.0f / s1 : 0.0f;
  }
  __syncthreads();                        // P_sh + f_sh visible to all waves

  // ---- phase 3: MFMA aggregation (A from LDS, B straight from global) ----
  const int nt = wv & 3, kh = wv >> 2;
  const int arow = lane & 15, agrp = lane >> 4;
  const int bcol = nt * 16 + (lane & 15);
  const unsigned short* nbrow = nbT + ((size_t)(b * 64 + bcol)) * 512;

  f32x4 C = {0.f, 0.f, 0.f, 0.f};
  #pragma unroll
  for (int ks = 0; ks < 8; ++ks) {
    const int jb = kh * 256 + ks * 32 + agrp * 8;
    short8 afr = *(const short8*)&P_sh[arow][jb];
    short8 bfr = *(const short8*)(nbrow + jb);
    C = __builtin_amdgcn_mfma_f32_16x16x32_bf16(afr, bfr, C, 0, 0, 0);
  }
  if (kh == 1) *(f32x4*)&red_sh[wv - 4][lane][0] = C;
  __syncthreads();
  if (kh == 0) {
    f32x4 P = *(const f32x4*)&red_sh[wv][lane][0];
    #pragma unroll
    for (int r = 0; r < 4; ++r) {
      const int rg = agrp * 4 + r;        // C/D: row = (lane>>4)*4 + reg
      const float f = f_sh[rg];
      const size_t adr = (nodeb + i0 + rg) * 64 + bcol;
      const float val = (C[r] + P[r]) * f + self_e[adr];
      out[adr] = (f > 0.f) ? val : 0.f;
    }
  }
}

// ---------------------------------------------------------------------------
extern "C" void kernel_launch(void* const* d_in, const int* in_sizes, int n_in,
                              void* d_out, int out_size, void* d_ws, size_t ws_size,
                              hipStream_t stream) {
  const float* nodes   = (const float*)d_in[0];
  const int*   edges   = (const int*)  d_in[1];
  const float* self_w1 = (const float*)d_in[2];
  const float* self_b1 = (const float*)d_in[3];
  const float* self_w2 = (const float*)d_in[4];
  const float* self_b2 = (const float*)d_in[5];
  const float* nb_w1   = (const float*)d_in[6];
  const float* nb_b1   = (const float*)d_in[7];
  const float* nb_w2   = (const float*)d_in[8];
  const float* nb_b2   = (const float*)d_in[9];
  const float* comb_w1 = (const float*)d_in[10];
  const float* comb_b1 = (const float*)d_in[11];
  const float* comb_w2 = (const float*)d_in[12];
  const float* comb_b2 = (const float*)d_in[13];

  float* ws     = (float*)d_ws;
  float* self_e = ws;                       // 262144 floats
  float* ss     = ws + 262144;              // 262144
  float* sn     = ws + 524288;              // 262144 (row-major [b][j][k])
  float* sP     = ws + 786432;              // 4096
  float* sQ     = ws + 790528;              // 4096
  unsigned short* nbT = (unsigned short*)(ws + 794624);        // 524288 B
  unsigned long long* ep = (unsigned long long*)(ws + 925696); // 262144 B

  prep<<<576, 256, 0, stream>>>(
      nodes, edges, self_w1, self_b1, self_w2, self_b2,
      nb_w1, nb_b1, nb_w2, nb_b2, comb_w1, comb_b1, comb_w2, comb_b2,
      self_e, ss, sn, sP, sQ, nbT, ep);

  gat_attn<<<256, 512, 0, stream>>>(
      ep, comb_w2, self_e, ss, sn, sP, sQ, nbT, (float*)d_out);
}

// Round 9
// 35.792 us; speedup vs baseline: 1.2248x; 1.2248x over previous
//
#include <hip/hip_runtime.h>
#include <float.h>

typedef __attribute__((ext_vector_type(8))) short short8;
typedef __attribute__((ext_vector_type(4))) float f32x4;

#define SLOPE 0.2f
// leaky(t) = 0.6t + 0.4|t| for slope 0.2

__device__ __forceinline__ float leaky(float x) { return fmaxf(x, SLOPE * x); }

// f32 -> bf16 round-to-nearest-even
__device__ __forceinline__ unsigned short f2bf(float f) {
  unsigned u = __float_as_uint(f);
  return (unsigned short)((u + 0x7FFFu + ((u >> 16) & 1u)) >> 16);
}

// ---------------------------------------------------------------------------
// Kernel A "prep": node MLPs, 512 blocks x 256 thr, 8 nodes/block, 2/wave.
// Barriers minimized: h_sh/e_sh deps are WAVE-LOCAL (each wave reads only
// rows it wrote -> lgkmcnt ordering suffices, no __syncthreads needed).
// Only 2 block barriers: after x_sh cooperative load, before nbT pack.
// Outputs (all coalesced):
//   ss  = self_e @ comb_w1[:64] + comb_b1
//   sn  = nb_e   @ comb_w1[64:]
//   sP  = 0.6*sum_k(w2_k*ss_k) + comb_b2 ; sQ = 0.6*sum_k(w2_k*sn_k)
//   nbT3[b][j>>3][h][j&7] = bf16(nb_e[b][j][h])   (tiled, 1KB/block store)
// ---------------------------------------------------------------------------
__global__ __launch_bounds__(256) void prep(
    const float* __restrict__ nodes,
    const float* __restrict__ self_w1, const float* __restrict__ self_b1,
    const float* __restrict__ self_w2, const float* __restrict__ self_b2,
    const float* __restrict__ nb_w1,   const float* __restrict__ nb_b1,
    const float* __restrict__ nb_w2,   const float* __restrict__ nb_b2,
    const float* __restrict__ comb_w1, const float* __restrict__ comb_b1,
    const float* __restrict__ comb_w2, const float* __restrict__ comb_b2,
    float* __restrict__ self_e, float* __restrict__ ss, float* __restrict__ sn,
    float* __restrict__ sP, float* __restrict__ sQ,
    unsigned short* __restrict__ nbT)
{
  __shared__ float x_sh[8][128];
  __shared__ float h_sh[8][64];
  __shared__ float e_sh[8][64];

  const int tid = threadIdx.x, lane = tid & 63, wv = tid >> 6;
  const int node0 = blockIdx.x * 8;
  const int bb = node0 >> 9;          // batch
  const int jloc = node0 & 511;       // batch-local node base

  ((float4*)&x_sh[0][0])[tid] = ((const float4*)(nodes + (size_t)node0 * 128))[tid];
  __syncthreads();                    // barrier 1 (x_sh)

  const int la = wv * 2, lb = la + 1;
  const float w2lane = comb_w2[lane];
  const float cb2 = comb_b2[0];
  const float cb1 = comb_b1[lane];

  for (int p = 0; p < 2; ++p) {
    const float* w1 = p ? nb_w1 : self_w1;
    const float* b1 = p ? nb_b1 : self_b1;
    const float* w2 = p ? nb_w2 : self_w2;
    const float* b2 = p ? nb_b2 : self_b2;
    const float* cw = comb_w1 + (p ? 64 * 64 : 0);

    // ---- layer 1 (wave-local; no barrier after) ----
    float a0 = 0.f, a1 = 0.f, c0 = 0.f, c1 = 0.f;
    #pragma unroll 4
    for (int q = 0; q < 32; ++q) {
      float4 xa = *(const float4*)&x_sh[la][q * 4];
      float4 xb = *(const float4*)&x_sh[lb][q * 4];
      float w_0 = w1[(q * 4 + 0) * 64 + lane];
      float w_1 = w1[(q * 4 + 1) * 64 + lane];
      float w_2 = w1[(q * 4 + 2) * 64 + lane];
      float w_3 = w1[(q * 4 + 3) * 64 + lane];
      a0 += xa.x * w_0; a1 += xa.y * w_1; a0 += xa.z * w_2; a1 += xa.w * w_3;
      c0 += xb.x * w_0; c1 += xb.y * w_1; c0 += xb.z * w_2; c1 += xb.w * w_3;
    }
    {
      float bv = b1[lane];
      h_sh[la][lane] = leaky(a0 + a1 + bv);
      h_sh[lb][lane] = leaky(c0 + c1 + bv);
    }

    // ---- layer 2 (reads only this wave's h_sh rows) ----
    a0 = a1 = c0 = c1 = 0.f;
    #pragma unroll 4
    for (int q = 0; q < 16; ++q) {
      float4 ha = *(const float4*)&h_sh[la][q * 4];
      float4 hb = *(const float4*)&h_sh[lb][q * 4];
      float w_0 = w2[(q * 4 + 0) * 64 + lane];
      float w_1 = w2[(q * 4 + 1) * 64 + lane];
      float w_2 = w2[(q * 4 + 2) * 64 + lane];
      float w_3 = w2[(q * 4 + 3) * 64 + lane];
      a0 += ha.x * w_0; a1 += ha.y * w_1; a0 += ha.z * w_2; a1 += ha.w * w_3;
      c0 += hb.x * w_0; c1 += hb.y * w_1; c0 += hb.z * w_2; c1 += hb.w * w_3;
    }
    float e_a, e_b;
    {
      float bv = b2[lane];
      e_a = a0 + a1 + bv;
      e_b = c0 + c1 + bv;
    }
    e_sh[la][lane] = e_a;
    e_sh[lb][lane] = e_b;
    if (p == 0) {
      self_e[(size_t)(node0 + la) * 64 + lane] = e_a;
      self_e[(size_t)(node0 + lb) * 64 + lane] = e_b;
    }

    // ---- projection (reads only this wave's e_sh rows) ----
    a0 = a1 = c0 = c1 = 0.f;
    #pragma unroll 4
    for (int q = 0; q < 16; ++q) {
      float4 ea = *(const float4*)&e_sh[la][q * 4];
      float4 eb = *(const float4*)&e_sh[lb][q * 4];
      float w_0 = cw[(q * 4 + 0) * 64 + lane];
      float w_1 = cw[(q * 4 + 1) * 64 + lane];
      float w_2 = cw[(q * 4 + 2) * 64 + lane];
      float w_3 = cw[(q * 4 + 3) * 64 + lane];
      a0 += ea.x * w_0; a1 += ea.y * w_1; a0 += ea.z * w_2; a1 += ea.w * w_3;
      c0 += eb.x * w_0; c1 += eb.y * w_1; c0 += eb.z * w_2; c1 += eb.w * w_3;
    }
    float s_a = a0 + a1 + (p ? 0.f : cb1);
    float s_b = c0 + c1 + (p ? 0.f : cb1);
    {
      float* so = p ? sn : ss;
      so[(size_t)(node0 + la) * 64 + lane] = s_a;
      so[(size_t)(node0 + lb) * 64 + lane] = s_b;
    }
    float ra = w2lane * s_a, rb = w2lane * s_b;
    #pragma unroll
    for (int off = 32; off; off >>= 1) {
      ra += __shfl_xor(ra, off);
      rb += __shfl_xor(rb, off);
    }
    if (lane == 0) {
      float* po = p ? sQ : sP;
      float add = p ? 0.f : cb2;
      po[node0 + la] = 0.6f * ra + add;
      po[node0 + lb] = 0.6f * rb + add;
    }

    if (p == 1) {
      __syncthreads();                // barrier 2 (e_sh = nb_e from all waves)
      // nbT3 tile [64 h][8 j] = 1KB, fully coalesced block store
      const int h = tid >> 2, j2 = (tid & 3) * 2;
      unsigned pack = (unsigned)f2bf(e_sh[j2][h])
                    | ((unsigned)f2bf(e_sh[j2 + 1][h]) << 16);
      *(unsigned*)(nbT + ((size_t)(bb * 64 + (jloc >> 3))) * 512 + h * 8 + j2) = pack;
    }
  }
}

// ---------------------------------------------------------------------------
// Kernel B: 256 blocks (b = blk&7), 16 rows/block, 512 thr (8 waves).
// Wave wv owns rows {2wv, 2wv+1}: scores in registers, in-wave softmax,
// bf16 P -> LDS, MFMA aggregation (B from tiled nbT3, L2-hot).
// Edge masks computed inline: thread owns column j = tid, loads its 16 edge
// ints (4 x int4) at kernel top -> 16-bit mask in jm_sh (no epack pass).
// ---------------------------------------------------------------------------
__global__ __launch_bounds__(512) void gat_attn(
    const int* __restrict__ edges,
    const float* __restrict__ comb_w2,
    const float* __restrict__ self_e,
    const float* __restrict__ ss, const float* __restrict__ sn,
    const float* __restrict__ sP, const float* __restrict__ sQ,
    const unsigned short* __restrict__ nbT,
    float* __restrict__ out)
{
  __shared__ __align__(16) float sn_sh[2][64][68];          // 34.8 KB dbuf
  __shared__ __align__(16) unsigned short P_sh[16][520];    // 16.6 KB
  __shared__ __align__(16) float red_sh[4][64][4];          // 4 KB
  __shared__ unsigned short jm_sh[512];                     // 1 KB
  __shared__ float f_sh[16];

  const int tid = threadIdx.x, lane = tid & 63, wv = tid >> 6;
  const int b = blockIdx.x & 7, it = blockIdx.x >> 3;
  const int i0 = it * 16;
  const size_t nodeb = (size_t)b * 512;

  const int ra = wv * 2, rb = ra + 1;     // local rows (wave-owned)
  const int ia = i0 + ra, ib = ia + 1;    // batch-local rows

  // ---- edge mask for this thread's owned column j = tid (issued first) ----
  const int* eb = edges + ((size_t)(nodeb + tid)) * 512 + i0;
  const int4 ev0 = *(const int4*)(eb + 0);
  const int4 ev1 = *(const int4*)(eb + 4);
  const int4 ev2 = *(const int4*)(eb + 8);
  const int4 ev3 = *(const int4*)(eb + 12);

  // ---- hoists: w2p (0.4*w2), ss rows, sP, sQ ----
  float4 w2p[16], sa0[16], sa1[16];
  {
    const float4* w2v = (const float4*)comb_w2;
    const float4* s0 = (const float4*)(ss + (nodeb + ia) * 64);
    const float4* s1 = (const float4*)(ss + (nodeb + ib) * 64);
    #pragma unroll
    for (int q = 0; q < 16; ++q) {
      float4 w = w2v[q];
      w2p[q] = make_float4(0.4f * w.x, 0.4f * w.y, 0.4f * w.z, 0.4f * w.w);
      sa0[q] = s0[q];
      sa1[q] = s1[q];
    }
  }
  const float sPa = sP[nodeb + ia], sPb = sP[nodeb + ib];
  float sQv[8];
  #pragma unroll
  for (int jt = 0; jt < 8; ++jt) sQv[jt] = sQ[nodeb + jt * 64 + lane];

  // ---- finish mask -> jm_sh (covered by first staging barrier) ----
  {
    unsigned mj = 0;
    mj |= (ev0.x != 0 ? 1u : 0u) << 0;  mj |= (ev0.y != 0 ? 1u : 0u) << 1;
    mj |= (ev0.z != 0 ? 1u : 0u) << 2;  mj |= (ev0.w != 0 ? 1u : 0u) << 3;
    mj |= (ev1.x != 0 ? 1u : 0u) << 4;  mj |= (ev1.y != 0 ? 1u : 0u) << 5;
    mj |= (ev1.z != 0 ? 1u : 0u) << 6;  mj |= (ev1.w != 0 ? 1u : 0u) << 7;
    mj |= (ev2.x != 0 ? 1u : 0u) << 8;  mj |= (ev2.y != 0 ? 1u : 0u) << 9;
    mj |= (ev2.z != 0 ? 1u : 0u) << 10; mj |= (ev2.w != 0 ? 1u : 0u) << 11;
    mj |= (ev3.x != 0 ? 1u : 0u) << 12; mj |= (ev3.y != 0 ? 1u : 0u) << 13;
    mj |= (ev3.z != 0 ? 1u : 0u) << 14; mj |= (ev3.w != 0 ? 1u : 0u) << 15;
    const int d = tid - i0;             // self-loop i == j
    if (d >= 0 && d < 16) mj &= ~(1u << d);
    jm_sh[tid] = (unsigned short)mj;
  }

  // ---- phase 1: scores, double-buffered sn staging (1 barrier/tile) ----
  const int str = tid >> 4, stc = (tid & 15) * 4;
  const int str2 = (tid + 512) >> 4, stc2 = ((tid + 512) & 15) * 4;
  float4 st0, st1;
  {
    const float4* src = (const float4*)(sn + nodeb * 64);
    st0 = src[tid];
    st1 = src[tid + 512];
  }

  float msc0[8], msc1[8];
  int cur = 0;
  for (int jt = 0; jt < 8; ++jt) {
    *(float4*)&sn_sh[cur][str][stc] = st0;
    *(float4*)&sn_sh[cur][str2][stc2] = st1;
    if (jt < 7) {
      const float4* src = (const float4*)(sn + (nodeb + (jt + 1) * 64) * 64);
      st0 = src[tid];
      st1 = src[tid + 512];
    }
    __syncthreads();

    float acc0 = 0.f, acc1 = 0.f;
    #pragma unroll
    for (int q = 0; q < 16; ++q) {
      float4 v = *(const float4*)&sn_sh[cur][lane][q * 4];
      float4 w = w2p[q];
      float4 A = sa0[q];
      float4 Bv = sa1[q];
      acc0 += w.x * fabsf(A.x + v.x) + w.y * fabsf(A.y + v.y)
            + w.z * fabsf(A.z + v.z) + w.w * fabsf(A.w + v.w);
      acc1 += w.x * fabsf(Bv.x + v.x) + w.y * fabsf(Bv.y + v.y)
            + w.z * fabsf(Bv.z + v.z) + w.w * fabsf(Bv.w + v.w);
    }
    const unsigned mj = jm_sh[jt * 64 + lane];
    msc0[jt] = ((mj >> ra) & 1u) ? acc0 + sPa + sQv[jt] : -FLT_MAX;
    msc1[jt] = ((mj >> rb) & 1u) ? acc1 + sPb + sQv[jt] : -FLT_MAX;
    cur ^= 1;
  }

  // ---- phase 2: in-wave softmax (rows wholly owned by this wave) ----
  float m0 = msc0[0], m1 = msc1[0];
  #pragma unroll
  for (int jt = 1; jt < 8; ++jt) {
    m0 = fmaxf(m0, msc0[jt]);
    m1 = fmaxf(m1, msc1[jt]);
  }
  #pragma unroll
  for (int off = 32; off; off >>= 1) {
    m0 = fmaxf(m0, __shfl_xor(m0, off));
    m1 = fmaxf(m1, __shfl_xor(m1, off));
  }

  float s0 = 0.f, s1 = 0.f;
  #pragma unroll
  for (int jt = 0; jt < 8; ++jt) {
    const float e0 = __expf(msc0[jt] - m0);
    const float e1 = __expf(msc1[jt] - m1);
    P_sh[ra][jt * 64 + lane] = f2bf(e0);
    P_sh[rb][jt * 64 + lane] = f2bf(e1);
    s0 += e0;
    s1 += e1;
  }
  #pragma unroll
  for (int off = 32; off; off >>= 1) {
    s0 += __shfl_xor(s0, off);
    s1 += __shfl_xor(s1, off);
  }
  if (lane == 0) {
    f_sh[ra] = (m0 > -1e37f) ? 1.0f / s0 : 0.0f;
    f_sh[rb] = (m1 > -1e37f) ? 1.0f / s1 : 0.0f;
  }
  __syncthreads();                        // P_sh + f_sh visible to all waves

  // ---- phase 3: MFMA aggregation (A from LDS, B from tiled nbT3) ----
  const int nt = wv & 3, kh = wv >> 2;
  const int arow = lane & 15, agrp = lane >> 4;
  const int bcol = nt * 16 + (lane & 15);
  const unsigned short* nb3 = nbT + (size_t)b * 32768 + bcol * 8;

  f32x4 C = {0.f, 0.f, 0.f, 0.f};
  #pragma unroll
  for (int ks = 0; ks < 8; ++ks) {
    const int jb = kh * 256 + ks * 32 + agrp * 8;
    short8 afr = *(const short8*)&P_sh[arow][jb];
    short8 bfr = *(const short8*)(nb3 + (size_t)jb * 64);
    C = __builtin_amdgcn_mfma_f32_16x16x32_bf16(afr, bfr, C, 0, 0, 0);
  }
  if (kh == 1) *(f32x4*)&red_sh[wv - 4][lane][0] = C;
  __syncthreads();
  if (kh == 0) {
    f32x4 P = *(const f32x4*)&red_sh[wv][lane][0];
    #pragma unroll
    for (int r = 0; r < 4; ++r) {
      const int rg = agrp * 4 + r;        // C/D: row = (lane>>4)*4 + reg
      const float f = f_sh[rg];
      const size_t adr = (nodeb + i0 + rg) * 64 + bcol;
      const float val = (C[r] + P[r]) * f + self_e[adr];
      out[adr] = (f > 0.f) ? val : 0.f;
    }
  }
}

// ---------------------------------------------------------------------------
extern "C" void kernel_launch(void* const* d_in, const int* in_sizes, int n_in,
                              void* d_out, int out_size, void* d_ws, size_t ws_size,
                              hipStream_t stream) {
  const float* nodes   = (const float*)d_in[0];
  const int*   edges   = (const int*)  d_in[1];
  const float* self_w1 = (const float*)d_in[2];
  const float* self_b1 = (const float*)d_in[3];
  const float* self_w2 = (const float*)d_in[4];
  const float* self_b2 = (const float*)d_in[5];
  const float* nb_w1   = (const float*)d_in[6];
  const float* nb_b1   = (const float*)d_in[7];
  const float* nb_w2   = (const float*)d_in[8];
  const float* nb_b2   = (const float*)d_in[9];
  const float* comb_w1 = (const float*)d_in[10];
  const float* comb_b1 = (const float*)d_in[11];
  const float* comb_w2 = (const float*)d_in[12];
  const float* comb_b2 = (const float*)d_in[13];

  float* ws     = (float*)d_ws;
  float* self_e = ws;                       // 262144 floats
  float* ss     = ws + 262144;              // 262144
  float* sn     = ws + 524288;              // 262144 (row-major [b][j][k])
  float* sP     = ws + 786432;              // 4096
  float* sQ     = ws + 790528;              // 4096
  unsigned short* nbT = (unsigned short*)(ws + 794624);  // 512 KB, tiled

  prep<<<512, 256, 0, stream>>>(
      nodes, self_w1, self_b1, self_w2, self_b2,
      nb_w1, nb_b1, nb_w2, nb_b2, comb_w1, comb_b1, comb_w2, comb_b2,
      self_e, ss, sn, sP, sQ, nbT);

  gat_attn<<<256, 512, 0, stream>>>(
      edges, comb_w2, self_e, ss, sn, sP, sQ, nbT, (float*)d_out);
}

// Round 10
// 34.470 us; speedup vs baseline: 1.2718x; 1.0383x over previous
//
#include <hip/hip_runtime.h>
#include <float.h>

typedef __attribute__((ext_vector_type(8))) short short8;
typedef __attribute__((ext_vector_type(4))) float f32x4;

#define SLOPE 0.2f
// leaky(t) = 0.6t + 0.4|t| for slope 0.2

__device__ __forceinline__ float leaky(float x) { return fmaxf(x, SLOPE * x); }

// f32 -> bf16 round-to-nearest-even
__device__ __forceinline__ unsigned short f2bf(float f) {
  unsigned u = __float_as_uint(f);
  return (unsigned short)((u + 0x7FFFu + ((u >> 16) & 1u)) >> 16);
}

// ---------------------------------------------------------------------------
// Kernel 0 "wprep": 1 block x 1024 thr. Convert the 5 weight matrices to bf16
// MFMA-B-fragment order (verified layout: col = lane&15, k = (lane>>4)*8+j).
// Frag table (64 frags x 64 lanes x 8 bf16 = 64 KB):
//   path p base = p*32:  w1 -> +0  (16 frags: nt*4+kb, K=128)
//                        w2 -> +16 ( 8 frags: nt*2+kb, K=64)
//                        cw -> +24 ( 8 frags: nt*2+kb, K=64)
// ---------------------------------------------------------------------------
__global__ __launch_bounds__(1024) void wprep(
    const float* __restrict__ self_w1, const float* __restrict__ self_w2,
    const float* __restrict__ nb_w1,   const float* __restrict__ nb_w2,
    const float* __restrict__ comb_w1,
    unsigned short* __restrict__ wf)
{
  const int tid = threadIdx.x;
  #pragma unroll
  for (int u = 0; u < 4; ++u) {
    const int pair = tid * 4 + u;          // 0..4095
    const int frag = pair >> 6, lane = pair & 63;
    const int p = frag >> 5, fl = frag & 31;
    const float* src;
    int nt, kb;
    if (fl < 16)      { src = p ? nb_w1 : self_w1; nt = fl >> 2;        kb = fl & 3; }
    else if (fl < 24) { src = p ? nb_w2 : self_w2; nt = (fl - 16) >> 1; kb = (fl - 16) & 1; }
    else              { src = comb_w1 + p * 4096;  nt = (fl - 24) >> 1; kb = (fl - 24) & 1; }
    const int n = nt * 16 + (lane & 15);
    const int k0 = kb * 32 + (lane >> 4) * 8;
    unsigned short v[8];
    #pragma unroll
    for (int j = 0; j < 8; ++j) v[j] = f2bf(src[(k0 + j) * 64 + n]);
    short8 pk;
    #pragma unroll
    for (int j = 0; j < 8; ++j) pk[j] = (short)v[j];
    *(short8*)(wf + ((size_t)(frag * 64 + lane)) * 8) = pk;
  }
}

// ---------------------------------------------------------------------------
// Kernel 1 "mlp": 256 blocks x 64 thr (one wave = one 16-node tile, zero
// barriers). All three layers as bf16 MFMA 16x16x32; D->A transposes through
// a padded LDS tile [16][68] (2-way banks = free). Emits:
//   self_e, ss, sn (row-major), sP/sQ (rank-1 from frags), and nbT in the
//   attn B-fragment tiled layout [b][j>>3][h][j&7] (coalesced 1KB stores).
// ---------------------------------------------------------------------------
__global__ __launch_bounds__(64) void mlp(
    const float* __restrict__ nodes,
    const float* __restrict__ self_b1, const float* __restrict__ self_b2,
    const float* __restrict__ nb_b1,   const float* __restrict__ nb_b2,
    const float* __restrict__ comb_b1, const float* __restrict__ comb_w2,
    const float* __restrict__ comb_b2,
    const unsigned short* __restrict__ wf,
    float* __restrict__ self_e, float* __restrict__ ss, float* __restrict__ sn,
    float* __restrict__ sP, float* __restrict__ sQ,
    unsigned short* __restrict__ nbT)
{
  __shared__ float tile[16][68];

  const int lane = threadIdx.x;
  const int arow = lane & 15, agrp = lane >> 4;
  const int node0 = blockIdx.x * 16;       // global node base
  const int b = node0 >> 9, jloc = node0 & 511;

  // ---- x A-frags: 4 kblks, 8 consecutive f32 each -> bf16x8 ----
  short8 xa[4];
  {
    const float* xrow = nodes + ((size_t)(node0 + arow)) * 128 + agrp * 8;
    #pragma unroll
    for (int kb = 0; kb < 4; ++kb) {
      float v[8];
      *(float4*)&v[0] = *(const float4*)(xrow + kb * 32);
      *(float4*)&v[4] = *(const float4*)(xrow + kb * 32 + 4);
      #pragma unroll
      for (int j = 0; j < 8; ++j) xa[kb][j] = (short)f2bf(v[j]);
    }
  }

  const float w2v = comb_w2[arow + 0 * 16];  // per-nt below
  float w2vn[4], cb1v[4];
  #pragma unroll
  for (int nt = 0; nt < 4; ++nt) {
    w2vn[nt] = comb_w2[nt * 16 + arow];
    cb1v[nt] = comb_b1[nt * 16 + arow];
  }
  const float cb2 = comb_b2[0];
  (void)w2v;

  for (int p = 0; p < 2; ++p) {
    const float* b1 = p ? nb_b1 : self_b1;
    const float* b2 = p ? nb_b2 : self_b2;
    const unsigned short* wfp = wf + (size_t)p * 32 * 64 * 8;

    // ---- load weight fragments (coalesced ushort8) ----
    short8 w1f[16], w2f[8], cwf[8];
    #pragma unroll
    for (int i = 0; i < 16; ++i)
      w1f[i] = *(const short8*)(wfp + ((size_t)(i * 64 + lane)) * 8);
    #pragma unroll
    for (int i = 0; i < 8; ++i)
      w2f[i] = *(const short8*)(wfp + ((size_t)((16 + i) * 64 + lane)) * 8);
    #pragma unroll
    for (int i = 0; i < 8; ++i)
      cwf[i] = *(const short8*)(wfp + ((size_t)((24 + i) * 64 + lane)) * 8);

    // ---- layer 1: h = leaky(x @ w1 + b1) ----
    f32x4 acc[4];
    #pragma unroll
    for (int nt = 0; nt < 4; ++nt) acc[nt] = (f32x4){0.f, 0.f, 0.f, 0.f};
    #pragma unroll
    for (int kb = 0; kb < 4; ++kb)
      #pragma unroll
      for (int nt = 0; nt < 4; ++nt)
        acc[nt] = __builtin_amdgcn_mfma_f32_16x16x32_bf16(xa[kb], w1f[nt * 4 + kb], acc[nt], 0, 0, 0);
    #pragma unroll
    for (int nt = 0; nt < 4; ++nt) {
      const float bv = b1[nt * 16 + arow];
      #pragma unroll
      for (int r = 0; r < 4; ++r)
        tile[agrp * 4 + r][nt * 16 + arow] = leaky(acc[nt][r] + bv);
    }

    // ---- h A-frags from LDS ----
    short8 ha[2];
    #pragma unroll
    for (int kb = 0; kb < 2; ++kb) {
      float v[8];
      *(float4*)&v[0] = *(const float4*)&tile[arow][kb * 32 + agrp * 8];
      *(float4*)&v[4] = *(const float4*)&tile[arow][kb * 32 + agrp * 8 + 4];
      #pragma unroll
      for (int j = 0; j < 8; ++j) ha[kb][j] = (short)f2bf(v[j]);
    }

    // ---- layer 2: e = h @ w2 + b2 ----
    #pragma unroll
    for (int nt = 0; nt < 4; ++nt) acc[nt] = (f32x4){0.f, 0.f, 0.f, 0.f};
    #pragma unroll
    for (int kb = 0; kb < 2; ++kb)
      #pragma unroll
      for (int nt = 0; nt < 4; ++nt)
        acc[nt] = __builtin_amdgcn_mfma_f32_16x16x32_bf16(ha[kb], w2f[nt * 2 + kb], acc[nt], 0, 0, 0);
    #pragma unroll
    for (int nt = 0; nt < 4; ++nt) {
      const float bv = b2[nt * 16 + arow];
      #pragma unroll
      for (int r = 0; r < 4; ++r) {
        const float ev = acc[nt][r] + bv;
        tile[agrp * 4 + r][nt * 16 + arow] = ev;
        if (p == 0)
          self_e[((size_t)(node0 + agrp * 4 + r)) * 64 + nt * 16 + arow] = ev;
      }
    }

    // ---- e A-frags from LDS ----
    short8 ea[2];
    #pragma unroll
    for (int kb = 0; kb < 2; ++kb) {
      float v[8];
      *(float4*)&v[0] = *(const float4*)&tile[arow][kb * 32 + agrp * 8];
      *(float4*)&v[4] = *(const float4*)&tile[arow][kb * 32 + agrp * 8 + 4];
      #pragma unroll
      for (int j = 0; j < 8; ++j) ea[kb][j] = (short)f2bf(v[j]);
    }

    // ---- nbF pack (p==1): nbT[b][j>>3][h=lane][j&7], coalesced 1KB ----
    if (p == 1) {
      #pragma unroll
      for (int g = 0; g < 2; ++g) {
        short8 pk;
        #pragma unroll
        for (int jj = 0; jj < 8; ++jj)
          pk[jj] = (short)f2bf(tile[g * 8 + jj][lane]);
        *(short8*)(nbT + (size_t)b * 32768 + ((size_t)((jloc >> 3) + g)) * 512 + lane * 8) = pk;
      }
    }

    // ---- projection: s = e @ cw (+ comb_b1 for self) ----
    #pragma unroll
    for (int nt = 0; nt < 4; ++nt) acc[nt] = (f32x4){0.f, 0.f, 0.f, 0.f};
    #pragma unroll
    for (int kb = 0; kb < 2; ++kb)
      #pragma unroll
      for (int nt = 0; nt < 4; ++nt)
        acc[nt] = __builtin_amdgcn_mfma_f32_16x16x32_bf16(ea[kb], cwf[nt * 2 + kb], acc[nt], 0, 0, 0);

    float* so = p ? sn : ss;
    float t[4] = {0.f, 0.f, 0.f, 0.f};
    #pragma unroll
    for (int nt = 0; nt < 4; ++nt) {
      #pragma unroll
      for (int r = 0; r < 4; ++r) {
        const float sv = acc[nt][r] + (p ? 0.f : cb1v[nt]);
        so[((size_t)(node0 + agrp * 4 + r)) * 64 + nt * 16 + arow] = sv;
        t[r] += w2vn[nt] * sv;
      }
    }
    // rank-1 reduce within each 16-lane group
    #pragma unroll
    for (int r = 0; r < 4; ++r) {
      #pragma unroll
      for (int off = 1; off < 16; off <<= 1) t[r] += __shfl_xor(t[r], off);
    }
    if (arow == 0) {
      float* po = p ? sQ : sP;
      const float add = p ? 0.f : cb2;
      #pragma unroll
      for (int r = 0; r < 4; ++r)
        po[node0 + agrp * 4 + r] = 0.6f * t[r] + add;
    }
  }
}

// ---------------------------------------------------------------------------
// Kernel B: 256 blocks (b = blk&7), 16 rows/block, 512 thr (8 waves).
// (unchanged from R9 — verified) scores in registers, in-wave softmax,
// bf16 P -> LDS, MFMA aggregation (B from tiled nbT, L2-hot), inline masks.
// ---------------------------------------------------------------------------
__global__ __launch_bounds__(512) void gat_attn(
    const int* __restrict__ edges,
    const float* __restrict__ comb_w2,
    const float* __restrict__ self_e,
    const float* __restrict__ ss, const float* __restrict__ sn,
    const float* __restrict__ sP, const float* __restrict__ sQ,
    const unsigned short* __restrict__ nbT,
    float* __restrict__ out)
{
  __shared__ __align__(16) float sn_sh[2][64][68];          // 34.8 KB dbuf
  __shared__ __align__(16) unsigned short P_sh[16][520];    // 16.6 KB
  __shared__ __align__(16) float red_sh[4][64][4];          // 4 KB
  __shared__ unsigned short jm_sh[512];                     // 1 KB
  __shared__ float f_sh[16];

  const int tid = threadIdx.x, lane = tid & 63, wv = tid >> 6;
  const int b = blockIdx.x & 7, it = blockIdx.x >> 3;
  const int i0 = it * 16;
  const size_t nodeb = (size_t)b * 512;

  const int ra = wv * 2, rb = ra + 1;     // local rows (wave-owned)
  const int ia = i0 + ra, ib = ia + 1;    // batch-local rows

  // ---- edge mask for this thread's owned column j = tid (issued first) ----
  const int* ebp = edges + ((size_t)(nodeb + tid)) * 512 + i0;
  const int4 ev0 = *(const int4*)(ebp + 0);
  const int4 ev1 = *(const int4*)(ebp + 4);
  const int4 ev2 = *(const int4*)(ebp + 8);
  const int4 ev3 = *(const int4*)(ebp + 12);

  // ---- hoists: w2p (0.4*w2), ss rows, sP, sQ ----
  float4 w2p[16], sa0[16], sa1[16];
  {
    const float4* w2v = (const float4*)comb_w2;
    const float4* s0 = (const float4*)(ss + (nodeb + ia) * 64);
    const float4* s1 = (const float4*)(ss + (nodeb + ib) * 64);
    #pragma unroll
    for (int q = 0; q < 16; ++q) {
      float4 w = w2v[q];
      w2p[q] = make_float4(0.4f * w.x, 0.4f * w.y, 0.4f * w.z, 0.4f * w.w);
      sa0[q] = s0[q];
      sa1[q] = s1[q];
    }
  }
  const float sPa = sP[nodeb + ia], sPb = sP[nodeb + ib];
  float sQv[8];
  #pragma unroll
  for (int jt = 0; jt < 8; ++jt) sQv[jt] = sQ[nodeb + jt * 64 + lane];

  // ---- finish mask -> jm_sh (covered by first staging barrier) ----
  {
    unsigned mj = 0;
    mj |= (ev0.x != 0 ? 1u : 0u) << 0;  mj |= (ev0.y != 0 ? 1u : 0u) << 1;
    mj |= (ev0.z != 0 ? 1u : 0u) << 2;  mj |= (ev0.w != 0 ? 1u : 0u) << 3;
    mj |= (ev1.x != 0 ? 1u : 0u) << 4;  mj |= (ev1.y != 0 ? 1u : 0u) << 5;
    mj |= (ev1.z != 0 ? 1u : 0u) << 6;  mj |= (ev1.w != 0 ? 1u : 0u) << 7;
    mj |= (ev2.x != 0 ? 1u : 0u) << 8;  mj |= (ev2.y != 0 ? 1u : 0u) << 9;
    mj |= (ev2.z != 0 ? 1u : 0u) << 10; mj |= (ev2.w != 0 ? 1u : 0u) << 11;
    mj |= (ev3.x != 0 ? 1u : 0u) << 12; mj |= (ev3.y != 0 ? 1u : 0u) << 13;
    mj |= (ev3.z != 0 ? 1u : 0u) << 14; mj |= (ev3.w != 0 ? 1u : 0u) << 15;
    const int d = tid - i0;             // self-loop i == j
    if (d >= 0 && d < 16) mj &= ~(1u << d);
    jm_sh[tid] = (unsigned short)mj;
  }

  // ---- phase 1: scores, double-buffered sn staging (1 barrier/tile) ----
  const int str = tid >> 4, stc = (tid & 15) * 4;
  const int str2 = (tid + 512) >> 4, stc2 = ((tid + 512) & 15) * 4;
  float4 st0, st1;
  {
    const float4* src = (const float4*)(sn + nodeb * 64);
    st0 = src[tid];
    st1 = src[tid + 512];
  }

  float msc0[8], msc1[8];
  int cur = 0;
  for (int jt = 0; jt < 8; ++jt) {
    *(float4*)&sn_sh[cur][str][stc] = st0;
    *(float4*)&sn_sh[cur][str2][stc2] = st1;
    if (jt < 7) {
      const float4* src = (const float4*)(sn + (nodeb + (jt + 1) * 64) * 64);
      st0 = src[tid];
      st1 = src[tid + 512];
    }
    __syncthreads();

    float acc0 = 0.f, acc1 = 0.f;
    #pragma unroll
    for (int q = 0; q < 16; ++q) {
      float4 v = *(const float4*)&sn_sh[cur][lane][q * 4];
      float4 w = w2p[q];
      float4 A = sa0[q];
      float4 Bv = sa1[q];
      acc0 += w.x * fabsf(A.x + v.x) + w.y * fabsf(A.y + v.y)
            + w.z * fabsf(A.z + v.z) + w.w * fabsf(A.w + v.w);
      acc1 += w.x * fabsf(Bv.x + v.x) + w.y * fabsf(Bv.y + v.y)
            + w.z * fabsf(Bv.z + v.z) + w.w * fabsf(Bv.w + v.w);
    }
    const unsigned mj = jm_sh[jt * 64 + lane];
    msc0[jt] = ((mj >> ra) & 1u) ? acc0 + sPa + sQv[jt] : -FLT_MAX;
    msc1[jt] = ((mj >> rb) & 1u) ? acc1 + sPb + sQv[jt] : -FLT_MAX;
    cur ^= 1;
  }

  // ---- phase 2: in-wave softmax (rows wholly owned by this wave) ----
  float m0 = msc0[0], m1 = msc1[0];
  #pragma unroll
  for (int jt = 1; jt < 8; ++jt) {
    m0 = fmaxf(m0, msc0[jt]);
    m1 = fmaxf(m1, msc1[jt]);
  }
  #pragma unroll
  for (int off = 32; off; off >>= 1) {
    m0 = fmaxf(m0, __shfl_xor(m0, off));
    m1 = fmaxf(m1, __shfl_xor(m1, off));
  }

  float s0 = 0.f, s1 = 0.f;
  #pragma unroll
  for (int jt = 0; jt < 8; ++jt) {
    const float e0 = __expf(msc0[jt] - m0);
    const float e1 = __expf(msc1[jt] - m1);
    P_sh[ra][jt * 64 + lane] = f2bf(e0);
    P_sh[rb][jt * 64 + lane] = f2bf(e1);
    s0 += e0;
    s1 += e1;
  }
  #pragma unroll
  for (int off = 32; off; off >>= 1) {
    s0 += __shfl_xor(s0, off);
    s1 += __shfl_xor(s1, off);
  }
  if (lane == 0) {
    f_sh[ra] = (m0 > -1e37f) ? 1.0f / s0 : 0.0f;
    f_sh[rb] = (m1 > -1e37f) ? 1.0f / s1 : 0.0f;
  }
  __syncthreads();                        // P_sh + f_sh visible to all waves

  // ---- phase 3: MFMA aggregation (A from LDS, B from tiled nbT) ----
  const int nt = wv & 3, kh = wv >> 2;
  const int arow = lane & 15, agrp = lane >> 4;
  const int bcol = nt * 16 + (lane & 15);
  const unsigned short* nb3 = nbT + (size_t)b * 32768 + bcol * 8;

  f32x4 C = {0.f, 0.f, 0.f, 0.f};
  #pragma unroll
  for (int ks = 0; ks < 8; ++ks) {
    const int jb = kh * 256 + ks * 32 + agrp * 8;
    short8 afr = *(const short8*)&P_sh[arow][jb];
    short8 bfr = *(const short8*)(nb3 + (size_t)jb * 64);
    C = __builtin_amdgcn_mfma_f32_16x16x32_bf16(afr, bfr, C, 0, 0, 0);
  }
  if (kh == 1) *(f32x4*)&red_sh[wv - 4][lane][0] = C;
  __syncthreads();
  if (kh == 0) {
    f32x4 P = *(const f32x4*)&red_sh[wv][lane][0];
    #pragma unroll
    for (int r = 0; r < 4; ++r) {
      const int rg = agrp * 4 + r;        // C/D: row = (lane>>4)*4 + reg
      const float f = f_sh[rg];
      const size_t adr = (nodeb + i0 + rg) * 64 + bcol;
      const float val = (C[r] + P[r]) * f + self_e[adr];
      out[adr] = (f > 0.f) ? val : 0.f;
    }
  }
}

// ---------------------------------------------------------------------------
extern "C" void kernel_launch(void* const* d_in, const int* in_sizes, int n_in,
                              void* d_out, int out_size, void* d_ws, size_t ws_size,
                              hipStream_t stream) {
  const float* nodes   = (const float*)d_in[0];
  const int*   edges   = (const int*)  d_in[1];
  const float* self_w1 = (const float*)d_in[2];
  const float* self_b1 = (const float*)d_in[3];
  const float* self_w2 = (const float*)d_in[4];
  const float* self_b2 = (const float*)d_in[5];
  const float* nb_w1   = (const float*)d_in[6];
  const float* nb_b1   = (const float*)d_in[7];
  const float* nb_w2   = (const float*)d_in[8];
  const float* nb_b2   = (const float*)d_in[9];
  const float* comb_w1 = (const float*)d_in[10];
  const float* comb_b1 = (const float*)d_in[11];
  const float* comb_w2 = (const float*)d_in[12];
  const float* comb_b2 = (const float*)d_in[13];

  float* ws     = (float*)d_ws;
  float* self_e = ws;                       // 262144 floats
  float* ss     = ws + 262144;              // 262144
  float* sn     = ws + 524288;              // 262144 (row-major [b][j][k])
  float* sP     = ws + 786432;              // 4096
  float* sQ     = ws + 790528;              // 4096
  unsigned short* nbT = (unsigned short*)(ws + 794624);  // 512 KB, tiled
  unsigned short* wf  = (unsigned short*)(ws + 925696);  // 64 KB frag weights

  wprep<<<1, 1024, 0, stream>>>(self_w1, self_w2, nb_w1, nb_w2, comb_w1, wf);

  mlp<<<256, 64, 0, stream>>>(
      nodes, self_b1, self_b2, nb_b1, nb_b2, comb_b1, comb_w2, comb_b2,
      wf, self_e, ss, sn, sP, sQ, nbT);

  gat_attn<<<256, 512, 0, stream>>>(
      edges, comb_w2, self_e, ss, sn, sP, sQ, nbT, (float*)d_out);
}